// Round 1
// baseline (276.613 us; speedup 1.0000x reference)
//
#include <hip/hip_runtime.h>
#include <hip/hip_bf16.h>
#include <stdint.h>

#define DEVINL __device__ __forceinline__

typedef __attribute__((ext_vector_type(4))) float f32x4;
typedef __attribute__((ext_vector_type(8))) __bf16 bfv8;
typedef __attribute__((ext_vector_type(8))) short s16x8;
typedef __attribute__((ext_vector_type(4))) short s16x4;

// ---- helpers ----
DEVINL short f2bf(float f) {  // fp32 -> bf16 bits, RTNE
  union { float f; unsigned u; } v; v.f = f;
  unsigned r = v.u + 0x7FFFu + ((v.u >> 16) & 1u);
  return (short)(r >> 16);
}
DEVINL float bf2f(short h) {
  union { unsigned u; float f; } v; v.u = ((unsigned)(unsigned short)h) << 16;
  return v.f;
}
DEVINL void gload_lds16(const void* g, void* l) {
  // 16B direct global->LDS. LDS dest is wave-uniform base + lane*16.
  __builtin_amdgcn_global_load_lds((__attribute__((address_space(1))) unsigned*)(g),
                                   (__attribute__((address_space(3))) unsigned*)(l),
                                   16, 0, 0);
}

// ---- sizes (fixed by the problem) ----
// B=4, S=2048, D=U=1024

// ============ W transpose + cast: WT[n][k] = bf16(W[k][n]) ============
__global__ __launch_bounds__(256) void wt_kernel(
    const float* __restrict__ Wq, const float* __restrict__ Wk, const float* __restrict__ Wv,
    short* __restrict__ WTq, short* __restrict__ WTk, short* __restrict__ WTv) {
  __shared__ float tile[64][65];
  const float* W = (blockIdx.z == 0) ? Wq : (blockIdx.z == 1) ? Wk : Wv;
  short* WT = (blockIdx.z == 0) ? WTq : (blockIdx.z == 1) ? WTk : WTv;
  const int k0 = (blockIdx.x & 15) << 6;
  const int n0 = (blockIdx.x >> 4) << 6;
  const int c = threadIdx.x & 63, r0 = threadIdx.x >> 6;
#pragma unroll
  for (int i = 0; i < 16; ++i) {
    int r = (i << 2) + r0;
    tile[r][c] = W[(size_t)(k0 + r) * 1024 + n0 + c];
  }
  __syncthreads();
#pragma unroll
  for (int i = 0; i < 16; ++i) {
    int a = (i << 2) + r0;
    WT[(size_t)(n0 + a) * 1024 + k0 + c] = f2bf(tile[c][a]);
  }
}

// ============ Projection GEMM: C[8192,1024] = A_f32[8192,1024] @ WT^T + bias ============
// A staged fp32 to LDS (global_load_lds), converted to bf16 at fragment read.
// B source is WT [n][k] bf16 (row-major), staged linearly -> contiguous-k frags.
// OUTMODE 0: out row-major bf16 [8192][1024]  (Qb, Kb)
// OUTMODE 1: out transposed bf16 VT[b][u][t]  (V for the PV GEMM)
template <int OUTMODE>
__global__ __launch_bounds__(256) void proj_kernel(
    const float* __restrict__ A, const short* __restrict__ BT,
    const float* __restrict__ bias, short* __restrict__ out) {
  __shared__ float Asf[128 * 64];  // 32 KB
  __shared__ short Bs[128 * 64];   // 16 KB
  const int tid = threadIdx.x;
  const int w = tid >> 6, l = tid & 63;
  const int bm = blockIdx.x >> 3, bn = blockIdx.x & 7;
  const int m0 = bm << 7, n0 = bn << 7;
  const int wm = w >> 1, wn = w & 1;
  const int lr = l & 15, lk = (l >> 4) << 3;
  f32x4 acc[4][4] = {};
  for (int kt = 0; kt < 16; ++kt) {
#pragma unroll
    for (int i = 0; i < 8; ++i) {  // A: 2048 x 16B chunks, fp32 [128][64]
      const int c = ((i << 2) + w) * 64 + l;
      const int row = c >> 4, col = (c & 15) << 2;
      gload_lds16(A + (size_t)(m0 + row) * 1024 + (kt << 6) + col,
                  (char*)Asf + (size_t)((i << 2) + w) * 1024);
    }
#pragma unroll
    for (int i = 0; i < 4; ++i) {  // B: 1024 x 16B chunks, bf16 [128][64]
      const int c = ((i << 2) + w) * 64 + l;
      const int row = c >> 3, col = (c & 7) << 3;
      gload_lds16(BT + (size_t)(n0 + row) * 1024 + (kt << 6) + col,
                  (char*)Bs + (size_t)((i << 2) + w) * 1024);
    }
    __syncthreads();
#pragma unroll
    for (int ks = 0; ks < 2; ++ks) {
      bfv8 af[4], bfr[4];
#pragma unroll
      for (int mi = 0; mi < 4; ++mi) {
        const float* ap = &Asf[(wm * 64 + mi * 16 + lr) * 64 + ks * 32 + lk];
        f32x4 x0 = *(const f32x4*)ap;
        f32x4 x1 = *(const f32x4*)(ap + 4);
        bfv8 a;
#pragma unroll
        for (int j = 0; j < 4; ++j) { a[j] = (__bf16)x0[j]; a[j + 4] = (__bf16)x1[j]; }
        af[mi] = a;
      }
#pragma unroll
      for (int ni = 0; ni < 4; ++ni)
        bfr[ni] = *(const bfv8*)&Bs[(wn * 64 + ni * 16 + lr) * 64 + ks * 32 + lk];
#pragma unroll
      for (int mi = 0; mi < 4; ++mi)
#pragma unroll
        for (int ni = 0; ni < 4; ++ni)
          acc[mi][ni] = __builtin_amdgcn_mfma_f32_16x16x32_bf16(af[mi], bfr[ni], acc[mi][ni], 0, 0, 0);
    }
    __syncthreads();
  }
#pragma unroll
  for (int ni = 0; ni < 4; ++ni) {
    const int ng = n0 + wn * 64 + ni * 16 + lr;
    const float bv = bias[ng];
#pragma unroll
    for (int mi = 0; mi < 4; ++mi) {
      const int r0 = m0 + wm * 64 + mi * 16 + ((l >> 4) << 2);
      if (OUTMODE == 0) {
#pragma unroll
        for (int j = 0; j < 4; ++j)
          out[(size_t)(r0 + j) * 1024 + ng] = f2bf(acc[mi][ni][j] + bv);
      } else {
        const int b = r0 >> 11, t = r0 & 2047;
        s16x4 pk;
#pragma unroll
        for (int j = 0; j < 4; ++j) pk[j] = f2bf(acc[mi][ni][j] + bv);
        *(s16x4*)(out + ((size_t)b * 1024 + ng) * 2048 + t) = pk;
      }
    }
  }
}

// ============ bf16 GEMM: C = A[M,K] @ Bsrc^T, Bsrc is [N][K] row-major ============
// EPI 0: bf16 out, scaled by 1/32 (QK^T -> scores)
// EPI 1: f32 out (PV -> final output)
template <int LDA, int LDB, int LDC, int NBN, int NKT, int EPI, int SA, int SB, int SC>
__global__ __launch_bounds__(256) void gemm_bf16_kernel(
    const short* __restrict__ A, const short* __restrict__ Bsrc, void* __restrict__ Cout) {
  __shared__ short As[128 * 64];
  __shared__ short Bs[128 * 64];
  const int tid = threadIdx.x;
  const int w = tid >> 6, l = tid & 63;
  const int bm = blockIdx.x / NBN, bn = blockIdx.x % NBN;
  const int m0 = bm << 7, n0 = bn << 7;
  const int wm = w >> 1, wn = w & 1;
  const int lr = l & 15, lk = (l >> 4) << 3;
  A += (size_t)blockIdx.y * SA;
  Bsrc += (size_t)blockIdx.y * SB;
  f32x4 acc[4][4] = {};
  for (int kt = 0; kt < NKT; ++kt) {
#pragma unroll
    for (int i = 0; i < 4; ++i) {
      const int c = ((i << 2) + w) * 64 + l;
      const int row = c >> 3, col = (c & 7) << 3;
      gload_lds16(A + (size_t)(m0 + row) * LDA + (kt << 6) + col,
                  (char*)As + (size_t)((i << 2) + w) * 1024);
      gload_lds16(Bsrc + (size_t)(n0 + row) * LDB + (kt << 6) + col,
                  (char*)Bs + (size_t)((i << 2) + w) * 1024);
    }
    __syncthreads();
#pragma unroll
    for (int ks = 0; ks < 2; ++ks) {
      bfv8 af[4], bfr[4];
#pragma unroll
      for (int mi = 0; mi < 4; ++mi)
        af[mi] = *(const bfv8*)&As[(wm * 64 + mi * 16 + lr) * 64 + ks * 32 + lk];
#pragma unroll
      for (int ni = 0; ni < 4; ++ni)
        bfr[ni] = *(const bfv8*)&Bs[(wn * 64 + ni * 16 + lr) * 64 + ks * 32 + lk];
#pragma unroll
      for (int mi = 0; mi < 4; ++mi)
#pragma unroll
        for (int ni = 0; ni < 4; ++ni)
          acc[mi][ni] = __builtin_amdgcn_mfma_f32_16x16x32_bf16(af[mi], bfr[ni], acc[mi][ni], 0, 0, 0);
    }
    __syncthreads();
  }
  if (EPI == 0) {
    short* O = (short*)Cout + (size_t)blockIdx.y * SC;
#pragma unroll
    for (int mi = 0; mi < 4; ++mi) {
      const int r0 = m0 + wm * 64 + mi * 16 + ((l >> 4) << 2);
#pragma unroll
      for (int ni = 0; ni < 4; ++ni) {
        const int ng = n0 + wn * 64 + ni * 16 + lr;
#pragma unroll
        for (int j = 0; j < 4; ++j)
          O[(size_t)(r0 + j) * LDC + ng] = f2bf(acc[mi][ni][j] * 0.03125f);
      }
    }
  } else {
    float* O = (float*)Cout + (size_t)blockIdx.y * SC;
#pragma unroll
    for (int mi = 0; mi < 4; ++mi) {
      const int r0 = m0 + wm * 64 + mi * 16 + ((l >> 4) << 2);
#pragma unroll
      for (int ni = 0; ni < 4; ++ni) {
        const int ng = n0 + wn * 64 + ni * 16 + lr;
#pragma unroll
        for (int j = 0; j < 4; ++j)
          O[(size_t)(r0 + j) * LDC + ng] = acc[mi][ni][j];
      }
    }
  }
}

// ============ Row softmax, in-place on bf16 scores [B*S rows][2048] ============
__global__ __launch_bounds__(256) void softmax_kernel(short* __restrict__ Sb) {
  const size_t row = blockIdx.x;
  short* p = Sb + row * 2048;
  const int tid = threadIdx.x;
  const int w = tid >> 6, l = tid & 63;
  s16x8 v = *(const s16x8*)(p + tid * 8);
  float f[8];
#pragma unroll
  for (int j = 0; j < 8; ++j) f[j] = bf2f(v[j]);
  float m = f[0];
#pragma unroll
  for (int j = 1; j < 8; ++j) m = fmaxf(m, f[j]);
#pragma unroll
  for (int o = 32; o > 0; o >>= 1) m = fmaxf(m, __shfl_xor(m, o, 64));
  __shared__ float redm[4], reds[4];
  if (l == 0) redm[w] = m;
  __syncthreads();
  m = fmaxf(fmaxf(redm[0], redm[1]), fmaxf(redm[2], redm[3]));
  float s = 0.f;
#pragma unroll
  for (int j = 0; j < 8; ++j) { f[j] = __expf(f[j] - m); s += f[j]; }
#pragma unroll
  for (int o = 32; o > 0; o >>= 1) s += __shfl_xor(s, o, 64);
  if (l == 0) reds[w] = s;
  __syncthreads();
  s = reds[0] + reds[1] + reds[2] + reds[3];
  const float inv = 1.f / s;
  s16x8 o8;
#pragma unroll
  for (int j = 0; j < 8; ++j) o8[j] = f2bf(f[j] * inv);
  *(s16x8*)(p + tid * 8) = o8;
}

// ============ launch ============
extern "C" void kernel_launch(void* const* d_in, const int* in_sizes, int n_in,
                              void* d_out, int out_size, void* d_ws, size_t ws_size,
                              hipStream_t stream) {
  const float* query = (const float*)d_in[0];
  const float* value = (const float*)d_in[1];
  const float* Wq = (const float*)d_in[2];
  const float* bq = (const float*)d_in[3];
  const float* Wk = (const float*)d_in[4];
  const float* bk = (const float*)d_in[5];
  const float* Wv = (const float*)d_in[6];
  const float* bv = (const float*)d_in[7];

  // Workspace layout (bytes), total 86 MB:
  //  WTq 0..2M, WTk 2..4M, WTv 4..6M            (bf16 W^T, [n][k])
  //  Qb  6..22M, Kb 22..38M                     (bf16 [b*s][u])
  //  VT  38..54M                                (bf16 [b][u][t])
  //  Sb  54..86M                                (bf16 scores -> P, [b][s][t])
  char* ws = (char*)d_ws;
  short* WTq = (short*)(ws);
  short* WTk = (short*)(ws + ((size_t)2 << 20));
  short* WTv = (short*)(ws + ((size_t)4 << 20));
  short* Qb  = (short*)(ws + ((size_t)6 << 20));
  short* Kb  = (short*)(ws + ((size_t)22 << 20));
  short* VT  = (short*)(ws + ((size_t)38 << 20));
  short* Sb  = (short*)(ws + ((size_t)54 << 20));

  wt_kernel<<<dim3(256, 1, 3), 256, 0, stream>>>(Wq, Wk, Wv, WTq, WTk, WTv);

  proj_kernel<0><<<dim3(512), 256, 0, stream>>>(query, WTq, bq, Qb);
  proj_kernel<0><<<dim3(512), 256, 0, stream>>>(value, WTk, bk, Kb);
  proj_kernel<1><<<dim3(512), 256, 0, stream>>>(value, WTv, bv, VT);

  // scores[b][s][t] = (Q . K) / 32
  gemm_bf16_kernel<1024, 1024, 2048, 16, 16, 0, 2097152, 2097152, 4194304>
      <<<dim3(256, 4), 256, 0, stream>>>(Qb, Kb, Sb);

  softmax_kernel<<<dim3(8192), 256, 0, stream>>>(Sb);

  // out[b][s][u] = P @ V  (V via VT[b][u][t])
  gemm_bf16_kernel<2048, 2048, 1024, 8, 32, 1, 4194304, 2097152, 2097152>
      <<<dim3(128, 4), 256, 0, stream>>>(Sb, VT, (float*)d_out);
}

// Round 2
// 212.675 us; speedup vs baseline: 1.3006x; 1.3006x over previous
//
#include <hip/hip_runtime.h>
#include <hip/hip_bf16.h>
#include <stdint.h>

#define DEVINL __device__ __forceinline__

typedef __attribute__((ext_vector_type(4))) float f32x4;
typedef __attribute__((ext_vector_type(8))) __bf16 bfv8;
typedef __attribute__((ext_vector_type(8))) short s16x8;
typedef __attribute__((ext_vector_type(4))) short s16x4;

// ---- helpers ----
DEVINL short f2bf(float f) {  // fp32 -> bf16 bits, RTNE
  union { float f; unsigned u; } v; v.f = f;
  unsigned r = v.u + 0x7FFFu + ((v.u >> 16) & 1u);
  return (short)(r >> 16);
}
DEVINL float bf2f(short h) {
  union { unsigned u; float f; } v; v.u = ((unsigned)(unsigned short)h) << 16;
  return v.f;
}
DEVINL void gload_lds16(const void* g, void* l) {
  // 16B direct global->LDS. LDS dest = wave-uniform base + lane*16.
  __builtin_amdgcn_global_load_lds((__attribute__((address_space(1))) unsigned*)(g),
                                   (__attribute__((address_space(3))) unsigned*)(l),
                                   16, 0, 0);
}
#define S_BARRIER() __builtin_amdgcn_s_barrier()
#define LGKM0() asm volatile("s_waitcnt lgkmcnt(0)" ::: "memory")
#define MEMORD() asm volatile("" ::: "memory")
DEVINL void vmwait(int n) {
  if (n >= 8) asm volatile("s_waitcnt vmcnt(8)" ::: "memory");
  else if (n >= 4) asm volatile("s_waitcnt vmcnt(4)" ::: "memory");
  else asm volatile("s_waitcnt vmcnt(0)" ::: "memory");
}

// ================= 256x256 tile, BK=32, 4-slot LDS ring, phase-interleaved core ==========
// 512 threads = 8 waves (2M x 4N); wave tile 128x64; acc[8][4] f32x4.
// LDS: 4 ring slots x (A 256x32 + B 256x32) bf16 = 4 x 32KB = 128 KB.
// Per K-tile: 2 phases x {ds_reads | 2 stage issues | barrier | lgkmcnt(0) | 16 MFMA | barrier}.
// Stage of K-tile kt+3 goes into slot (kt+3)&3 == (kt-1)&3, which was fully vacated at the
// barrier ending K-tile kt-1 (all reads lgkm-drained before their MFMA) -> no WAR race.
// vmcnt(8) once per K-tile (2 K-tiles = 8 loads stay in flight; never drained to 0 mid-loop).
// Bank swizzle (64B rows): storage chunk = logical chunk ^ ((row>>1)&3); applied as
// inverse-swizzled GLOBAL source (gload_lds writes linearly) + swizzled ds_read (rule 21).
DEVINL void gemm32_core(const short* __restrict__ Ag, const short* __restrict__ Bg,
                        int lda, int ldb, int m0, int n0, int nkt,
                        short* lds, f32x4 (&acc)[8][4]) {
  const int tid = threadIdx.x;
  const int w = tid >> 6, l = tid & 63;
  const int wm = w >> 2, wn = w & 3;
  const int lr = l & 15, lg = l >> 4;
  // staging: lane l covers storage row (l>>2), chunk (l&3) of each 128-row unit
  const int stg_row = w * 16 + (l >> 2);
  const int stg_col = (((l & 3) ^ ((l >> 3) & 3)) << 3);   // inverse-swizzled source col (elems)
  // fragment reads: 16B at row(+lr), logical chunk lg -> storage chunk lg ^ ((lr>>1)&3)
  const int ck = ((lg ^ ((lr >> 1) & 3)) << 3);
  const int aro = (wm * 128 + lr) * 32 + ck;   // + qh*2048 + mf*512
  const int bro = (wn * 64 + lr) * 32 + ck;    // + nf*512
  const int dU0 = (w * 16) * 32, dU1 = (128 + w * 16) * 32;  // wave-uniform LDS dest (shorts)

  // ---- prologue: stage K-tiles 0,1,2 (12 loads), wait tile0, barrier ----
#pragma unroll
  for (int t = 0; t < 3; ++t) {
    short* Ab = lds + t * 16384;
    short* Bb = Ab + 8192;
    gload_lds16(Ag + (size_t)(m0 + stg_row) * lda + t * 32 + stg_col, Ab + dU0);
    gload_lds16(Ag + (size_t)(m0 + 128 + stg_row) * lda + t * 32 + stg_col, Ab + dU1);
    gload_lds16(Bg + (size_t)(n0 + stg_row) * ldb + t * 32 + stg_col, Bb + dU0);
    gload_lds16(Bg + (size_t)(n0 + 128 + stg_row) * ldb + t * 32 + stg_col, Bb + dU1);
  }
  vmwait(8); S_BARRIER(); MEMORD();

  bfv8 a[4], b[4];
#pragma unroll 1
  for (int kt = 0; kt < nkt; ++kt) {
    const short* Ab = lds + (kt & 3) * 16384;
    const short* Bb = Ab + 8192;
    const int ks = kt + 3;
    short* sA = lds + (ks & 3) * 16384;
    short* sB = sA + 8192;
    // ---------- phase q0: rows [0,64) of wave tile ----------
#pragma unroll
    for (int mf = 0; mf < 4; ++mf) a[mf] = *(const bfv8*)(Ab + aro + mf * 512);
#pragma unroll
    for (int nf = 0; nf < 4; ++nf) b[nf] = *(const bfv8*)(Bb + bro + nf * 512);
    if (ks < nkt) {
      gload_lds16(Ag + (size_t)(m0 + stg_row) * lda + ks * 32 + stg_col, sA + dU0);
      gload_lds16(Ag + (size_t)(m0 + 128 + stg_row) * lda + ks * 32 + stg_col, sA + dU1);
    }
    S_BARRIER(); LGKM0();
    __builtin_amdgcn_s_setprio(1);
#pragma unroll
    for (int mf = 0; mf < 4; ++mf)
#pragma unroll
      for (int nf = 0; nf < 4; ++nf)
        acc[mf][nf] = __builtin_amdgcn_mfma_f32_16x16x32_bf16(a[mf], b[nf], acc[mf][nf], 0, 0, 0);
    __builtin_amdgcn_s_setprio(0);
    S_BARRIER(); MEMORD();
    // ---------- phase q1: rows [64,128) of wave tile ----------
#pragma unroll
    for (int mf = 0; mf < 4; ++mf) a[mf] = *(const bfv8*)(Ab + aro + 2048 + mf * 512);
    if (ks < nkt) {
      gload_lds16(Bg + (size_t)(n0 + stg_row) * ldb + ks * 32 + stg_col, sB + dU0);
      gload_lds16(Bg + (size_t)(n0 + 128 + stg_row) * ldb + ks * 32 + stg_col, sB + dU1);
    }
    if (kt + 1 < nkt) vmwait(ks < nkt ? 8 : (kt + 2 < nkt ? 4 : 0));
    S_BARRIER(); LGKM0();
    __builtin_amdgcn_s_setprio(1);
#pragma unroll
    for (int mf = 0; mf < 4; ++mf)
#pragma unroll
      for (int nf = 0; nf < 4; ++nf)
        acc[4 + mf][nf] = __builtin_amdgcn_mfma_f32_16x16x32_bf16(a[mf], b[nf], acc[4 + mf][nf], 0, 0, 0);
    __builtin_amdgcn_s_setprio(0);
    S_BARRIER(); MEMORD();
  }
}

// ============ cast fp32 -> bf16 (query, value) ============
__global__ __launch_bounds__(256) void cast_kernel(const float* __restrict__ q,
                                                   const float* __restrict__ v,
                                                   short* __restrict__ Qc, short* __restrict__ Vc) {
  const float* src = blockIdx.y ? v : q;
  short* dst = blockIdx.y ? Vc : Qc;
  const size_t i = ((size_t)blockIdx.x * 256 + threadIdx.x) * 8;
  f32x4 x0 = *(const f32x4*)(src + i);
  f32x4 x1 = *(const f32x4*)(src + i + 4);
  s16x8 o;
#pragma unroll
  for (int j = 0; j < 4; ++j) { o[j] = f2bf(x0[j]); o[4 + j] = f2bf(x1[j]); }
  *(s16x8*)(dst + i) = o;
}

// ============ W transpose + cast: WT[n][k] = bf16(W[k][n]) ============
__global__ __launch_bounds__(256) void wt_kernel(
    const float* __restrict__ Wq, const float* __restrict__ Wk, const float* __restrict__ Wv,
    short* __restrict__ WTq, short* __restrict__ WTk, short* __restrict__ WTv) {
  __shared__ float tile[64][65];
  const float* W = (blockIdx.z == 0) ? Wq : (blockIdx.z == 1) ? Wk : Wv;
  short* WT = (blockIdx.z == 0) ? WTq : (blockIdx.z == 1) ? WTk : WTv;
  const int k0 = (blockIdx.x & 15) << 6;
  const int n0 = (blockIdx.x >> 4) << 6;
  const int c = threadIdx.x & 63, r0 = threadIdx.x >> 6;
#pragma unroll
  for (int i = 0; i < 16; ++i) {
    int r = (i << 2) + r0;
    tile[r][c] = W[(size_t)(k0 + r) * 1024 + n0 + c];
  }
  __syncthreads();
#pragma unroll
  for (int i = 0; i < 16; ++i) {
    int a = (i << 2) + r0;
    WT[(size_t)(n0 + a) * 1024 + k0 + c] = f2bf(tile[c][a]);
  }
}

// ============ fused QKV projection: 384 blocks (12 N-panels x 32 M-blocks) ============
__global__ __launch_bounds__(512, 2) void proj8_kernel(
    const short* __restrict__ Qc, const short* __restrict__ Vc,
    const short* __restrict__ WTq, const short* __restrict__ WTk, const short* __restrict__ WTv,
    const float* __restrict__ bq, const float* __restrict__ bk, const float* __restrict__ bv,
    short* __restrict__ Qb, short* __restrict__ Kb, short* __restrict__ VT) {
  __shared__ short lds[65536];
  const int bm = blockIdx.x & 31, bn = blockIdx.x >> 5;  // bn 0..11
  const int sel = bn >> 2;
  const short* A = (sel == 0) ? Qc : Vc;
  const short* BT = (sel == 0) ? WTq : (sel == 1) ? WTk : WTv;
  const float* bias = (sel == 0) ? bq : (sel == 1) ? bk : bv;
  const int m0 = bm * 256, n0 = (bn & 3) * 256;
  f32x4 acc[8][4];
#pragma unroll
  for (int i = 0; i < 8; ++i)
#pragma unroll
    for (int j = 0; j < 4; ++j) acc[i][j] = (f32x4){0.f, 0.f, 0.f, 0.f};
  gemm32_core(A, BT, 1024, 1024, m0, n0, 32, lds, acc);
  const int tid = threadIdx.x;
  const int w = tid >> 6, l = tid & 63;
  const int wm = w >> 2, wn = w & 3, lr = l & 15, lg = l >> 4;
#pragma unroll
  for (int i = 0; i < 8; ++i) {
    const int row0 = m0 + wm * 128 + (i >> 2) * 64 + (i & 3) * 16 + lg * 4;
#pragma unroll
    for (int nf = 0; nf < 4; ++nf) {
      const int col = n0 + wn * 64 + nf * 16 + lr;
      const float bb = bias[col];
      if (sel < 2) {
        short* O = sel ? Kb : Qb;
#pragma unroll
        for (int j = 0; j < 4; ++j)
          O[(size_t)(row0 + j) * 1024 + col] = f2bf(acc[i][nf][j] + bb);
      } else {
        const int bidx = row0 >> 11, t = row0 & 2047;
        s16x4 pk;
#pragma unroll
        for (int j = 0; j < 4; ++j) pk[j] = f2bf(acc[i][nf][j] + bb);
        *(s16x4*)(VT + ((size_t)bidx * 1024 + col) * 2048 + t) = pk;
      }
    }
  }
}

// ============ QK^T: scores = (Q.K)/32, bf16 out ============
__global__ __launch_bounds__(512, 2) void qkt8_kernel(const short* __restrict__ Qb,
                                                      const short* __restrict__ Kb,
                                                      short* __restrict__ Sb) {
  __shared__ short lds[65536];
  const int bt = blockIdx.y;
  const int bm = blockIdx.x >> 3, bn = blockIdx.x & 7;
  const short* A = Qb + (size_t)bt * 2097152;
  const short* B = Kb + (size_t)bt * 2097152;
  short* O = Sb + (size_t)bt * 4194304;
  const int m0 = bm * 256, n0 = bn * 256;
  f32x4 acc[8][4];
#pragma unroll
  for (int i = 0; i < 8; ++i)
#pragma unroll
    for (int j = 0; j < 4; ++j) acc[i][j] = (f32x4){0.f, 0.f, 0.f, 0.f};
  gemm32_core(A, B, 1024, 1024, m0, n0, 32, lds, acc);
  const int tid = threadIdx.x;
  const int w = tid >> 6, l = tid & 63;
  const int wm = w >> 2, wn = w & 3, lr = l & 15, lg = l >> 4;
#pragma unroll
  for (int i = 0; i < 8; ++i) {
    const int row0 = m0 + wm * 128 + (i >> 2) * 64 + (i & 3) * 16 + lg * 4;
#pragma unroll
    for (int nf = 0; nf < 4; ++nf) {
      const int col = n0 + wn * 64 + nf * 16 + lr;
#pragma unroll
      for (int j = 0; j < 4; ++j)
        O[(size_t)(row0 + j) * 2048 + col] = f2bf(acc[i][nf][j] * 0.03125f);
    }
  }
}

// ============ PV: out = P @ V (V via VT[b][u][t]), fp32 out ============
__global__ __launch_bounds__(512, 2) void pv8_kernel(const short* __restrict__ Sb,
                                                     const short* __restrict__ VT,
                                                     float* __restrict__ Out) {
  __shared__ short lds[65536];
  const int bt = blockIdx.y;
  const int bm = blockIdx.x >> 2, bn = blockIdx.x & 3;
  const short* A = Sb + (size_t)bt * 4194304;
  const short* B = VT + (size_t)bt * 2097152;
  float* O = Out + (size_t)bt * 2097152;
  const int m0 = bm * 256, n0 = bn * 256;
  f32x4 acc[8][4];
#pragma unroll
  for (int i = 0; i < 8; ++i)
#pragma unroll
    for (int j = 0; j < 4; ++j) acc[i][j] = (f32x4){0.f, 0.f, 0.f, 0.f};
  gemm32_core(A, B, 2048, 2048, m0, n0, 64, lds, acc);
  const int tid = threadIdx.x;
  const int w = tid >> 6, l = tid & 63;
  const int wm = w >> 2, wn = w & 3, lr = l & 15, lg = l >> 4;
#pragma unroll
  for (int i = 0; i < 8; ++i) {
    const int row0 = m0 + wm * 128 + (i >> 2) * 64 + (i & 3) * 16 + lg * 4;
#pragma unroll
    for (int nf = 0; nf < 4; ++nf) {
      const int col = n0 + wn * 64 + nf * 16 + lr;
#pragma unroll
      for (int j = 0; j < 4; ++j)
        O[(size_t)(row0 + j) * 1024 + col] = acc[i][nf][j];
    }
  }
}

// ============ Row softmax, in-place on bf16 scores [B*S rows][2048] ============
__global__ __launch_bounds__(256) void softmax_kernel(short* __restrict__ Sb) {
  const size_t row = blockIdx.x;
  short* p = Sb + row * 2048;
  const int tid = threadIdx.x;
  const int w = tid >> 6, l = tid & 63;
  s16x8 v = *(const s16x8*)(p + tid * 8);
  float f[8];
#pragma unroll
  for (int j = 0; j < 8; ++j) f[j] = bf2f(v[j]);
  float m = f[0];
#pragma unroll
  for (int j = 1; j < 8; ++j) m = fmaxf(m, f[j]);
#pragma unroll
  for (int o = 32; o > 0; o >>= 1) m = fmaxf(m, __shfl_xor(m, o, 64));
  __shared__ float redm[4], reds[4];
  if (l == 0) redm[w] = m;
  __syncthreads();
  m = fmaxf(fmaxf(redm[0], redm[1]), fmaxf(redm[2], redm[3]));
  float s = 0.f;
#pragma unroll
  for (int j = 0; j < 8; ++j) { f[j] = __expf(f[j] - m); s += f[j]; }
#pragma unroll
  for (int o = 32; o > 0; o >>= 1) s += __shfl_xor(s, o, 64);
  if (l == 0) reds[w] = s;
  __syncthreads();
  s = reds[0] + reds[1] + reds[2] + reds[3];
  const float inv = 1.f / s;
  s16x8 o8;
#pragma unroll
  for (int j = 0; j < 8; ++j) o8[j] = f2bf(f[j] * inv);
  *(s16x8*)(p + tid * 8) = o8;
}

// ============ launch ============
extern "C" void kernel_launch(void* const* d_in, const int* in_sizes, int n_in,
                              void* d_out, int out_size, void* d_ws, size_t ws_size,
                              hipStream_t stream) {
  const float* query = (const float*)d_in[0];
  const float* value = (const float*)d_in[1];
  const float* Wq = (const float*)d_in[2];
  const float* bq = (const float*)d_in[3];
  const float* Wk = (const float*)d_in[4];
  const float* bk = (const float*)d_in[5];
  const float* Wv = (const float*)d_in[6];
  const float* bv = (const float*)d_in[7];

  // Workspace layout (86 MB total):
  //  0: WTq(2M) 2M: WTk(2M) 4M: WTv(2M)
  //  6M: region X (32MB): Qc@6M(16M), Vc@22M(16M) [projection inputs];
  //      later reused as Sb@6M(32MB) [scores/P] -- lifetimes disjoint (stream-ordered)
  //  38M: Qb(16M)  54M: Kb(16M)  70M: VT(16M)
  char* ws = (char*)d_ws;
  short* WTq = (short*)(ws);
  short* WTk = (short*)(ws + ((size_t)2 << 20));
  short* WTv = (short*)(ws + ((size_t)4 << 20));
  short* Qc  = (short*)(ws + ((size_t)6 << 20));
  short* Vc  = (short*)(ws + ((size_t)22 << 20));
  short* Sb  = (short*)(ws + ((size_t)6 << 20));
  short* Qb  = (short*)(ws + ((size_t)38 << 20));
  short* Kb  = (short*)(ws + ((size_t)54 << 20));
  short* VT  = (short*)(ws + ((size_t)70 << 20));

  cast_kernel<<<dim3(4096, 2), 256, 0, stream>>>(query, value, Qc, Vc);
  wt_kernel<<<dim3(256, 1, 3), 256, 0, stream>>>(Wq, Wk, Wv, WTq, WTk, WTv);

  // fused Q/K/V projections: N-panels 0-3 -> Qb, 4-7 -> Kb, 8-11 -> VT
  proj8_kernel<<<dim3(384), 512, 0, stream>>>(Qc, Vc, WTq, WTk, WTv, bq, bk, bv, Qb, Kb, VT);

  // scores[b][s][t] = (Q.K)/32
  qkt8_kernel<<<dim3(64, 4), 512, 0, stream>>>(Qb, Kb, Sb);

  softmax_kernel<<<dim3(8192), 256, 0, stream>>>(Sb);

  // out[b][s][u] = P @ V
  pv8_kernel<<<dim3(32, 4), 512, 0, stream>>>(Sb, VT, (float*)d_out);
}

// Round 3
// 208.558 us; speedup vs baseline: 1.3263x; 1.0197x over previous
//
#include <hip/hip_runtime.h>
#include <hip/hip_bf16.h>
#include <stdint.h>

#define DEVINL __device__ __forceinline__

typedef __attribute__((ext_vector_type(4))) float f32x4;
typedef __attribute__((ext_vector_type(8))) __bf16 bfv8;
typedef __attribute__((ext_vector_type(8))) short s16x8;
typedef __attribute__((ext_vector_type(4))) short s16x4;

// ---- helpers ----
DEVINL short f2bf(float f) {  // fp32 -> bf16 bits, RTNE
  union { float f; unsigned u; } v; v.f = f;
  unsigned r = v.u + 0x7FFFu + ((v.u >> 16) & 1u);
  return (short)(r >> 16);
}
DEVINL float bf2f(short h) {
  union { unsigned u; float f; } v; v.u = ((unsigned)(unsigned short)h) << 16;
  return v.f;
}
DEVINL void gload_lds16(const void* g, void* l) {
  // 16B direct global->LDS. LDS dest = wave-uniform base + lane*16.
  __builtin_amdgcn_global_load_lds((__attribute__((address_space(1))) unsigned*)(g),
                                   (__attribute__((address_space(3))) unsigned*)(l),
                                   16, 0, 0);
}
#define S_BARRIER() __builtin_amdgcn_s_barrier()
#define LGKM0() asm volatile("s_waitcnt lgkmcnt(0)" ::: "memory")
#define MEMORD() asm volatile("" ::: "memory")
template <int N> DEVINL void vmwaitc() {
  asm volatile("s_waitcnt vmcnt(%0)" :: "i"(N) : "memory");
}

// ================= 256(M) x (NF*64)(N) tile, BK=32, 4-slot LDS ring =================
// 512 threads = 8 waves (2M x 4N); wave tile 128 x (NF*16).
// Slot layout (shorts): A [256][32] = 8192, then B [BU*128][32] = BU*4096.
// Per K-tile: 2 phases x {ds_reads | stage issues | barrier | lgkmcnt(0) | MFMA | barrier}.
// Stage of tile kt+3 -> slot (kt+3)&3 == (kt-1)&3, vacated at end of kt-1 (no WAR).
// vmcnt(2U) once per K-tile (U = loads/K-tile = 2+BU); never drained to 0 mid-loop.
// Bank swizzle: storage chunk = logical chunk ^ ((row>>1)&3), applied as inverse-swizzled
// GLOBAL source + swizzled ds_read (both-sides rule). Verified: 0 bank conflicts (r2).
template <int BU, int NF>
DEVINL void gemm_core(const short* __restrict__ Ag, const short* __restrict__ Bg,
                      int lda, int ldb, int m0, int n0, int nkt,
                      short* lds, f32x4 (&acc)[8][NF]) {
  constexpr int U = 2 + BU;            // loads per K-tile
  constexpr int SLOT = 8192 + BU * 4096;
  const int tid = threadIdx.x;
  const int w = tid >> 6, l = tid & 63;
  const int wm = w >> 2, wn = w & 3;
  const int lr = l & 15, lg = l >> 4;
  const int stg_row = w * 16 + (l >> 2);
  const int stg_col = (((l & 3) ^ ((l >> 3) & 3)) << 3);   // inverse-swizzled source col
  const int ck = ((lg ^ ((lr >> 1) & 3)) << 3);            // swizzled read chunk
  const int aro = (wm * 128 + lr) * 32 + ck;               // + qh*2048 + mf*512
  const int bro = 8192 + (wn * (NF * 16) + lr) * 32 + ck;  // + nf*512
  const int dW = w * 512;                                  // wave-uniform LDS dest

  // ---- prologue: stage K-tiles 0,1,2; wait tile0; barrier ----
#pragma unroll
  for (int t = 0; t < 3; ++t) {
    short* S = lds + t * SLOT;
    gload_lds16(Ag + (size_t)(m0 + stg_row) * lda + t * 32 + stg_col, S + dW);
    gload_lds16(Ag + (size_t)(m0 + 128 + stg_row) * lda + t * 32 + stg_col, S + 4096 + dW);
#pragma unroll
    for (int u = 0; u < BU; ++u)
      gload_lds16(Bg + (size_t)(n0 + u * 128 + stg_row) * ldb + t * 32 + stg_col,
                  S + 8192 + u * 4096 + dW);
  }
  vmwaitc<2 * U>(); S_BARRIER(); MEMORD();

  bfv8 a[4], b[NF];
#pragma unroll 1
  for (int kt = 0; kt < nkt; ++kt) {
    const short* Sc = lds + (kt & 3) * SLOT;
    const int ks = kt + 3;
    short* Ss = lds + (ks & 3) * SLOT;
    // ---------- phase q0: rows [0,64) of wave tile ----------
#pragma unroll
    for (int mf = 0; mf < 4; ++mf) a[mf] = *(const bfv8*)(Sc + aro + mf * 512);
#pragma unroll
    for (int nf = 0; nf < NF; ++nf) b[nf] = *(const bfv8*)(Sc + bro + nf * 512);
    if (ks < nkt) {
      gload_lds16(Ag + (size_t)(m0 + stg_row) * lda + ks * 32 + stg_col, Ss + dW);
      gload_lds16(Ag + (size_t)(m0 + 128 + stg_row) * lda + ks * 32 + stg_col, Ss + 4096 + dW);
    }
    S_BARRIER(); LGKM0();
    __builtin_amdgcn_s_setprio(1);
#pragma unroll
    for (int mf = 0; mf < 4; ++mf)
#pragma unroll
      for (int nf = 0; nf < NF; ++nf)
        acc[mf][nf] = __builtin_amdgcn_mfma_f32_16x16x32_bf16(a[mf], b[nf], acc[mf][nf], 0, 0, 0);
    __builtin_amdgcn_s_setprio(0);
    S_BARRIER(); MEMORD();
    // ---------- phase q1: rows [64,128) of wave tile ----------
#pragma unroll
    for (int mf = 0; mf < 4; ++mf) a[mf] = *(const bfv8*)(Sc + aro + 2048 + mf * 512);
    if (ks < nkt) {
#pragma unroll
      for (int u = 0; u < BU; ++u)
        gload_lds16(Bg + (size_t)(n0 + u * 128 + stg_row) * ldb + ks * 32 + stg_col,
                    Ss + 8192 + u * 4096 + dW);
    }
    if (kt + 1 < nkt) {
      if (ks < nkt) vmwaitc<2 * U>();
      else if (kt + 2 < nkt) vmwaitc<U>();
      else vmwaitc<0>();
    }
    S_BARRIER(); LGKM0();
    __builtin_amdgcn_s_setprio(1);
#pragma unroll
    for (int mf = 0; mf < 4; ++mf)
#pragma unroll
      for (int nf = 0; nf < NF; ++nf)
        acc[4 + mf][nf] = __builtin_amdgcn_mfma_f32_16x16x32_bf16(a[mf], b[nf], acc[4 + mf][nf], 0, 0, 0);
    __builtin_amdgcn_s_setprio(0);
    S_BARRIER(); MEMORD();
  }
}

// ============ prep: cast fp32->bf16 (Q,V) fused with W transpose+cast ============
__global__ __launch_bounds__(256) void prep_kernel(
    const float* __restrict__ q, const float* __restrict__ v,
    const float* __restrict__ Wq, const float* __restrict__ Wk, const float* __restrict__ Wv,
    short* __restrict__ Qc, short* __restrict__ Vc,
    short* __restrict__ WTq, short* __restrict__ WTk, short* __restrict__ WTv) {
  __shared__ float tile[64][65];
  const int bx = blockIdx.x;
  if (bx < 8192) {
    const float* src = (bx < 4096) ? q : v;
    short* dst = (bx < 4096) ? Qc : Vc;
    const size_t i = ((size_t)(bx & 4095) * 256 + threadIdx.x) * 8;
    f32x4 x0 = *(const f32x4*)(src + i);
    f32x4 x1 = *(const f32x4*)(src + i + 4);
    s16x8 o;
#pragma unroll
    for (int j = 0; j < 4; ++j) { o[j] = f2bf(x0[j]); o[4 + j] = f2bf(x1[j]); }
    *(s16x8*)(dst + i) = o;
  } else {
    const int z = (bx - 8192) >> 8, xx = (bx - 8192) & 255;
    const float* W = (z == 0) ? Wq : (z == 1) ? Wk : Wv;
    short* WT = (z == 0) ? WTq : (z == 1) ? WTk : WTv;
    const int k0 = (xx & 15) << 6, n0 = (xx >> 4) << 6;
    const int c = threadIdx.x & 63, r0 = threadIdx.x >> 6;
#pragma unroll
    for (int i = 0; i < 16; ++i) {
      int r = (i << 2) + r0;
      tile[r][c] = W[(size_t)(k0 + r) * 1024 + n0 + c];
    }
    __syncthreads();
#pragma unroll
    for (int i = 0; i < 16; ++i) {
      int a = (i << 2) + r0;
      WT[(size_t)(n0 + a) * 1024 + k0 + c] = f2bf(tile[c][a]);
    }
  }
}

// ============ Q+K projections: grid 32(bm) x 8(bn) = 256 blocks exactly ============
__global__ __launch_bounds__(512, 2) void qkproj_kernel(
    const short* __restrict__ Qc, const short* __restrict__ Vc,
    const short* __restrict__ WTq, const short* __restrict__ WTk,
    const float* __restrict__ bq, const float* __restrict__ bk,
    short* __restrict__ Qb, short* __restrict__ Kb) {
  __shared__ short lds[65536];
  const int bm = blockIdx.x >> 3, bn = blockIdx.x & 7;
  const int sel = bn >> 2;
  const short* A = sel ? Vc : Qc;
  const short* BT = sel ? WTk : WTq;
  const float* bias = sel ? bk : bq;
  short* O = sel ? Kb : Qb;
  const int m0 = bm * 256, n0 = (bn & 3) * 256;
  f32x4 acc[8][4];
#pragma unroll
  for (int i = 0; i < 8; ++i)
#pragma unroll
    for (int j = 0; j < 4; ++j) acc[i][j] = (f32x4){0.f, 0.f, 0.f, 0.f};
  gemm_core<2, 4>(A, BT, 1024, 1024, m0, n0, 32, lds, acc);
  const int tid = threadIdx.x;
  const int w = tid >> 6, l = tid & 63;
  const int wm = w >> 2, wn = w & 3, lr = l & 15, lg = l >> 4;
#pragma unroll
  for (int i = 0; i < 8; ++i) {
    const int row0 = m0 + wm * 128 + (i >> 2) * 64 + (i & 3) * 16 + lg * 4;
#pragma unroll
    for (int nf = 0; nf < 4; ++nf) {
      const int col = n0 + wn * 64 + nf * 16 + lr;
      const float bb = bias[col];
#pragma unroll
      for (int j = 0; j < 4; ++j)
        O[(size_t)(row0 + j) * 1024 + col] = f2bf(acc[i][nf][j] + bb);
    }
  }
}

// ============ V projection -> VT[b][u][t]: grid 32(bm) x 8(bn) = 256 blocks ============
// N-tile = 128 (BU=1, NF=2). Epilogue: LDS transpose -> coalesced s16x8 stores along t.
__global__ __launch_bounds__(512, 2) void vproj_kernel(
    const short* __restrict__ Vc, const short* __restrict__ WTv,
    const float* __restrict__ bv, short* __restrict__ VT) {
  __shared__ short lds[49152];  // 96 KB: ring 4 x 12288; transpose reuse 128x264 = 33792
  const int bm = blockIdx.x >> 3, bn = blockIdx.x & 7;
  const int m0 = bm * 256, n0 = bn * 128;
  f32x4 acc[8][2];
#pragma unroll
  for (int i = 0; i < 8; ++i)
#pragma unroll
    for (int j = 0; j < 2; ++j) acc[i][j] = (f32x4){0.f, 0.f, 0.f, 0.f};
  gemm_core<1, 2>(Vc, WTv, 1024, 1024, m0, n0, 32, lds, acc);
  const int tid = threadIdx.x;
  const int w = tid >> 6, l = tid & 63;
  const int wm = w >> 2, wn = w & 3, lr = l & 15, lg = l >> 4;
  __syncthreads();
  // acc -> LDS [u_local 0..127][t_local 0..255], stride 264 (bank-spread)
#pragma unroll
  for (int i = 0; i < 8; ++i) {
    const int tl = wm * 128 + (i >> 2) * 64 + (i & 3) * 16 + lg * 4;
#pragma unroll
    for (int nf = 0; nf < 2; ++nf) {
      const int ul = wn * 32 + nf * 16 + lr;
      const float bb = bv[n0 + ul];
#pragma unroll
      for (int j = 0; j < 4; ++j)
        lds[ul * 264 + tl + j] = f2bf(acc[i][nf][j] + bb);
    }
  }
  __syncthreads();
  const int b = m0 >> 11, t0 = m0 & 2047;
#pragma unroll
  for (int it = 0; it < 8; ++it) {
    const int cid = it * 512 + tid;
    const int u = cid >> 5, tc = cid & 31;
    s16x8 v8 = *(const s16x8*)&lds[u * 264 + tc * 8];
    *(s16x8*)(VT + ((size_t)b * 1024 + n0 + u) * 2048 + t0 + tc * 8) = v8;
  }
}

// ============ QK^T: scores = (Q.K)/32, bf16 out; grid (64, 4) ============
__global__ __launch_bounds__(512, 2) void qkt8_kernel(const short* __restrict__ Qb,
                                                      const short* __restrict__ Kb,
                                                      short* __restrict__ Sb) {
  __shared__ short lds[65536];
  const int bt = blockIdx.y;
  const int bm = blockIdx.x >> 3, bn = blockIdx.x & 7;
  const short* A = Qb + (size_t)bt * 2097152;
  const short* B = Kb + (size_t)bt * 2097152;
  short* O = Sb + (size_t)bt * 4194304;
  const int m0 = bm * 256, n0 = bn * 256;
  f32x4 acc[8][4];
#pragma unroll
  for (int i = 0; i < 8; ++i)
#pragma unroll
    for (int j = 0; j < 4; ++j) acc[i][j] = (f32x4){0.f, 0.f, 0.f, 0.f};
  gemm_core<2, 4>(A, B, 1024, 1024, m0, n0, 32, lds, acc);
  const int tid = threadIdx.x;
  const int w = tid >> 6, l = tid & 63;
  const int wm = w >> 2, wn = w & 3, lr = l & 15, lg = l >> 4;
#pragma unroll
  for (int i = 0; i < 8; ++i) {
    const int row0 = m0 + wm * 128 + (i >> 2) * 64 + (i & 3) * 16 + lg * 4;
#pragma unroll
    for (int nf = 0; nf < 4; ++nf) {
      const int col = n0 + wn * 64 + nf * 16 + lr;
#pragma unroll
      for (int j = 0; j < 4; ++j)
        O[(size_t)(row0 + j) * 2048 + col] = f2bf(acc[i][nf][j] * 0.03125f);
    }
  }
}

// ============ PV: out = P @ V (V via VT[b][u][t]), fp32 out; grid (32, 4) ============
__global__ __launch_bounds__(512, 2) void pv8_kernel(const short* __restrict__ Sb,
                                                     const short* __restrict__ VT,
                                                     float* __restrict__ Out) {
  __shared__ short lds[65536];
  const int bt = blockIdx.y;
  const int bm = blockIdx.x >> 2, bn = blockIdx.x & 3;
  const short* A = Sb + (size_t)bt * 4194304;
  const short* B = VT + (size_t)bt * 2097152;
  float* O = Out + (size_t)bt * 2097152;
  const int m0 = bm * 256, n0 = bn * 256;
  f32x4 acc[8][4];
#pragma unroll
  for (int i = 0; i < 8; ++i)
#pragma unroll
    for (int j = 0; j < 4; ++j) acc[i][j] = (f32x4){0.f, 0.f, 0.f, 0.f};
  gemm_core<2, 4>(A, B, 2048, 2048, m0, n0, 64, lds, acc);
  const int tid = threadIdx.x;
  const int w = tid >> 6, l = tid & 63;
  const int wm = w >> 2, wn = w & 3, lr = l & 15, lg = l >> 4;
#pragma unroll
  for (int i = 0; i < 8; ++i) {
    const int row0 = m0 + wm * 128 + (i >> 2) * 64 + (i & 3) * 16 + lg * 4;
#pragma unroll
    for (int nf = 0; nf < 4; ++nf) {
      const int col = n0 + wn * 64 + nf * 16 + lr;
#pragma unroll
      for (int j = 0; j < 4; ++j)
        O[(size_t)(row0 + j) * 1024 + col] = acc[i][nf][j];
    }
  }
}

// ============ Row softmax, in-place on bf16 scores [B*S rows][2048] ============
__global__ __launch_bounds__(256) void softmax_kernel(short* __restrict__ Sb) {
  const size_t row = blockIdx.x;
  short* p = Sb + row * 2048;
  const int tid = threadIdx.x;
  const int w = tid >> 6, l = tid & 63;
  s16x8 v = *(const s16x8*)(p + tid * 8);
  float f[8];
#pragma unroll
  for (int j = 0; j < 8; ++j) f[j] = bf2f(v[j]);
  float m = f[0];
#pragma unroll
  for (int j = 1; j < 8; ++j) m = fmaxf(m, f[j]);
#pragma unroll
  for (int o = 32; o > 0; o >>= 1) m = fmaxf(m, __shfl_xor(m, o, 64));
  __shared__ float redm[4], reds[4];
  if (l == 0) redm[w] = m;
  __syncthreads();
  m = fmaxf(fmaxf(redm[0], redm[1]), fmaxf(redm[2], redm[3]));
  float s = 0.f;
#pragma unroll
  for (int j = 0; j < 8; ++j) { f[j] = __expf(f[j] - m); s += f[j]; }
#pragma unroll
  for (int o = 32; o > 0; o >>= 1) s += __shfl_xor(s, o, 64);
  if (l == 0) reds[w] = s;
  __syncthreads();
  s = reds[0] + reds[1] + reds[2] + reds[3];
  const float inv = 1.f / s;
  s16x8 o8;
#pragma unroll
  for (int j = 0; j < 8; ++j) o8[j] = f2bf(f[j] * inv);
  *(s16x8*)(p + tid * 8) = o8;
}

// ============ launch ============
extern "C" void kernel_launch(void* const* d_in, const int* in_sizes, int n_in,
                              void* d_out, int out_size, void* d_ws, size_t ws_size,
                              hipStream_t stream) {
  const float* query = (const float*)d_in[0];
  const float* value = (const float*)d_in[1];
  const float* Wq = (const float*)d_in[2];
  const float* bq = (const float*)d_in[3];
  const float* Wk = (const float*)d_in[4];
  const float* bk = (const float*)d_in[5];
  const float* Wv = (const float*)d_in[6];
  const float* bv = (const float*)d_in[7];

  // Workspace layout (86 MB total):
  //  0: WTq(2M) 2M: WTk(2M) 4M: WTv(2M)
  //  6M: region X (32MB): Qc@6M(16M), Vc@22M(16M) [projection inputs];
  //      later reused as Sb@6M(32MB) [scores/P] -- lifetimes disjoint (stream-ordered)
  //  38M: Qb(16M)  54M: Kb(16M)  70M: VT(16M)
  char* ws = (char*)d_ws;
  short* WTq = (short*)(ws);
  short* WTk = (short*)(ws + ((size_t)2 << 20));
  short* WTv = (short*)(ws + ((size_t)4 << 20));
  short* Qc  = (short*)(ws + ((size_t)6 << 20));
  short* Vc  = (short*)(ws + ((size_t)22 << 20));
  short* Sb  = (short*)(ws + ((size_t)6 << 20));
  short* Qb  = (short*)(ws + ((size_t)38 << 20));
  short* Kb  = (short*)(ws + ((size_t)54 << 20));
  short* VT  = (short*)(ws + ((size_t)70 << 20));

  prep_kernel<<<dim3(8960), 256, 0, stream>>>(query, value, Wq, Wk, Wv, Qc, Vc, WTq, WTk, WTv);

  qkproj_kernel<<<dim3(256), 512, 0, stream>>>(Qc, Vc, WTq, WTk, bq, bk, Qb, Kb);
  vproj_kernel<<<dim3(256), 512, 0, stream>>>(Vc, WTv, bv, VT);

  // scores[b][s][t] = (Q.K)/32
  qkt8_kernel<<<dim3(64, 4), 512, 0, stream>>>(Qb, Kb, Sb);

  softmax_kernel<<<dim3(8192), 256, 0, stream>>>(Sb);

  // out[b][s][u] = P @ V
  pv8_kernel<<<dim3(32, 4), 512, 0, stream>>>(Sb, VT, (float*)d_out);
}